// Round 1
// baseline (786.242 us; speedup 1.0000x reference)
//
#include <hip/hip_runtime.h>

typedef __bf16 bf16;
typedef __bf16 bf16x4 __attribute__((ext_vector_type(4)));
typedef __bf16 bf16x8 __attribute__((ext_vector_type(8)));
typedef float floatx4_t __attribute__((ext_vector_type(4)));

#define DEPTH_SCALE 0.4082482904638631f

__device__ __forceinline__ float fast_rcp(float x) { return __builtin_amdgcn_rcpf(x); }
__device__ __forceinline__ float fast_sigmoid(float x) { return fast_rcp(1.f + __expf(-x)); }
__device__ __forceinline__ float fast_tanh(float x) {
    float e = __expf(2.f * x);
    return 1.f - 2.f * fast_rcp(e + 1.f);
}

__device__ __forceinline__ void ld16(const void* g, void* l) {
    __builtin_amdgcn_global_load_lds((__attribute__((address_space(1))) void*)g,
                                     (__attribute__((address_space(3))) void*)l,
                                     16, 0, 0);
}

__device__ __forceinline__ float wave_reduce_add(float v) {
#pragma unroll
    for (int off = 1; off < 64; off <<= 1) v += __shfl_xor(v, off, 64);
    return v;
}

// ---------------- K0: transpose + cast f32 -> bf16 ----------------
// src: [batch][R][C] f32, dst: [batch][C][R] bf16. grid (C/32, R/32, batch), block (32,8)
__global__ __launch_bounds__(256) void transpose_cast(const float* __restrict__ src,
                                                      bf16* __restrict__ dst,
                                                      int R, int C) {
    __shared__ float tile[32][33];
    const int b = blockIdx.z;
    src += (size_t)b * R * C;
    dst += (size_t)b * R * C;
    const int tx = threadIdx.x, ty = threadIdx.y;
    const int c0 = blockIdx.x * 32, r0 = blockIdx.y * 32;
#pragma unroll
    for (int i = 0; i < 4; ++i) {
        int r = r0 + ty + i * 8;
        tile[ty + i * 8][tx] = src[(size_t)r * C + c0 + tx];
    }
    __syncthreads();
#pragma unroll
    for (int i = 0; i < 4; ++i) {
        int c = c0 + ty + i * 8;
        dst[(size_t)c * R + r0 + tx] = (bf16)tile[tx][ty + i * 8];
    }
}

// ---------------- K1: LayerNorm(x), LayerNorm(v), gate -> dt ----------------
// one block (256 thr = 4 waves) per token; wave w handles head w for the gate dot.
__global__ __launch_bounds__(256) void ln_gate_kernel(
    const float* __restrict__ x, const float* __restrict__ v,
    const float* __restrict__ lxg, const float* __restrict__ lxb,
    const float* __restrict__ lvg, const float* __restrict__ lvb,
    const float* __restrict__ gate_w, const float* __restrict__ gate_b,
    const float* __restrict__ dt_params,
    bf16* __restrict__ xnv, float* __restrict__ dtv) {
    const int t = blockIdx.x, tid = threadIdx.x;
    const int w = tid >> 6, lane = tid & 63;
    float4 xv = ((const float4*)(x + (size_t)t * 1024))[tid];
    float4 vv = ((const float4*)(v + (size_t)t * 1024))[tid];
    float sx = xv.x + xv.y + xv.z + xv.w;
    float qx = xv.x * xv.x + xv.y * xv.y + xv.z * xv.z + xv.w * xv.w;
    float sv = vv.x + vv.y + vv.z + vv.w;
    float qv = vv.x * vv.x + vv.y * vv.y + vv.z * vv.z + vv.w * vv.w;
    sx = wave_reduce_add(sx); qx = wave_reduce_add(qx);
    sv = wave_reduce_add(sv); qv = wave_reduce_add(qv);
    __shared__ float red[16];
    if (lane == 0) { red[w] = sx; red[4 + w] = qx; red[8 + w] = sv; red[12 + w] = qv; }
    __syncthreads();
    sx = red[0] + red[1] + red[2] + red[3];
    qx = red[4] + red[5] + red[6] + red[7];
    sv = red[8] + red[9] + red[10] + red[11];
    qv = red[12] + red[13] + red[14] + red[15];
    const float inv = 1.f / 1024.f;
    const float mx = sx * inv, varx = qx * inv - mx * mx;
    const float mv = sv * inv, varv = qv * inv - mv * mv;
    const float rx = rsqrtf(varx + 1e-5f), rv = rsqrtf(varv + 1e-5f);
    float4 gx4 = ((const float4*)lxg)[tid], bx4 = ((const float4*)lxb)[tid];
    float4 gv4 = ((const float4*)lvg)[tid], bv4 = ((const float4*)lvb)[tid];
    float xn[4] = { (xv.x - mx) * rx * gx4.x + bx4.x, (xv.y - mx) * rx * gx4.y + bx4.y,
                    (xv.z - mx) * rx * gx4.z + bx4.z, (xv.w - mx) * rx * gx4.w + bx4.w };
    float vn[4] = { (vv.x - mv) * rv * gv4.x + bv4.x, (vv.y - mv) * rv * gv4.y + bv4.y,
                    (vv.z - mv) * rv * gv4.z + bv4.z, (vv.w - mv) * rv * gv4.w + bv4.w };
    bf16x4 xs, vs;
#pragma unroll
    for (int j = 0; j < 4; ++j) { xs[j] = (bf16)xn[j]; vs[j] = (bf16)vn[j]; }
    *(bf16x4*)(xnv + (size_t)t * 2048 + tid * 4) = xs;
    *(bf16x4*)(xnv + (size_t)t * 2048 + 1024 + tid * 4) = vs;
    // gate: thread tid's 4 elements are all in head w (d = lane*4 .. +3)
    const int d0 = lane * 4;
    float4 gwx = *(const float4*)(gate_w + w * 512 + d0);
    float4 gwv = *(const float4*)(gate_w + w * 512 + 256 + d0);
    float p = xn[0] * gwx.x + xn[1] * gwx.y + xn[2] * gwx.z + xn[3] * gwx.w
            + vn[0] * gwv.x + vn[1] * gwv.y + vn[2] * gwv.z + vn[3] * gwv.w;
    p = wave_reduce_add(p);
    if (lane == 0) {
        float z = p + gate_b[w];
        float sp = log1pf(__expf(dt_params[w]));
        dtv[(size_t)t * 4 + w] = sp * 2.f * fast_sigmoid(z);
    }
}

// ---------------- K2: gamma = sigmoid(cat @ fric_w + fric_b), bf16 MFMA GEMM ----------------
// per head: M=16384 tokens, N=256, K=512. grid (128, 2, 4). m97-style 128x128 tile, BK=64.
__global__ __launch_bounds__(256) void gamma_gemm_kernel(
    const bf16* __restrict__ xnv, const bf16* __restrict__ fwt,
    const float* __restrict__ fric_b, bf16* __restrict__ gammab) {
    __shared__ bf16 sA[128 * 64];
    __shared__ bf16 sB[128 * 64];
    const int tid = threadIdx.x, w = tid >> 6, lane = tid & 63;
    const int wm = w >> 1, wn = w & 1;
    const int m0 = blockIdx.x * 128, n0 = blockIdx.y * 128, h = blockIdx.z;
    const int lrow = lane >> 3, lcol = (lane & 7) * 8;
    const int nl = lane & 15, quad = lane >> 4;
    floatx4_t acc[4][4];
    const floatx4_t z4 = {0.f, 0.f, 0.f, 0.f};
#pragma unroll
    for (int mi = 0; mi < 4; ++mi)
#pragma unroll
        for (int ni = 0; ni < 4; ++ni) acc[mi][ni] = z4;
    const bf16* Bh = fwt + (size_t)h * 256 * 512;
    for (int kt = 0; kt < 8; ++kt) {
        const int kg = kt * 64;
        const int colbase = (kg < 256) ? (h * 256 + kg) : (1024 + h * 256 + kg - 256);
#pragma unroll
        for (int i = 0; i < 4; ++i) {
            const int c = i * 4 + w;
            ld16(xnv + (size_t)(m0 + c * 8 + lrow) * 2048 + colbase + lcol, sA + c * 512);
            ld16(Bh + (size_t)(n0 + c * 8 + lrow) * 512 + kg + lcol, sB + c * 512);
        }
        __syncthreads();
#pragma unroll
        for (int kk = 0; kk < 2; ++kk) {
            bf16x8 af[4], bfr[4];
#pragma unroll
            for (int mi = 0; mi < 4; ++mi)
                af[mi] = *(const bf16x8*)(sA + (wm * 64 + mi * 16 + nl) * 64 + kk * 32 + quad * 8);
#pragma unroll
            for (int ni = 0; ni < 4; ++ni)
                bfr[ni] = *(const bf16x8*)(sB + (wn * 64 + ni * 16 + nl) * 64 + kk * 32 + quad * 8);
#pragma unroll
            for (int mi = 0; mi < 4; ++mi)
#pragma unroll
                for (int ni = 0; ni < 4; ++ni)
                    acc[mi][ni] = __builtin_amdgcn_mfma_f32_16x16x32_bf16(af[mi], bfr[ni], acc[mi][ni], 0, 0, 0);
        }
        __syncthreads();
    }
#pragma unroll
    for (int mi = 0; mi < 4; ++mi)
#pragma unroll
        for (int ni = 0; ni < 4; ++ni) {
            const int n = n0 + wn * 64 + ni * 16 + nl;  // head-local dim 0..255
            const float fb = fric_b[h * 256 + n];
#pragma unroll
            for (int r = 0; r < 4; ++r) {
                const int m = m0 + wm * 64 + mi * 16 + quad * 4 + r;
                gammab[(size_t)m * 1024 + h * 256 + n] = (bf16)fast_sigmoid(acc[mi][ni][r] + fb);
            }
        }
}

// ---------------- K3: Heun RK2 with low-rank Christoffel ----------------
__device__ __forceinline__ void acc_eval(const float* xq, const float* vq,
                                         const float* Uh, const float* Wxh, const float* Vph,
                                         int d0, const float* Fv, const float* gam, float* kv) {
    float sarr[16];
#pragma unroll
    for (int r = 0; r < 16; ++r) {
        float4 u = *(const float4*)(Uh + r * 256 + d0);
        float4 wxr = *(const float4*)(Wxh + r * 256 + d0);
        float pc = vq[0] * u.x + vq[1] * u.y + vq[2] * u.z + vq[3] * u.w;
        float pg = xq[0] * wxr.x + xq[1] * wxr.y + xq[2] * wxr.z + xq[3] * wxr.w;
#pragma unroll
        for (int off = 1; off < 64; off <<= 1) {
            pc += __shfl_xor(pc, off, 64);
            pg += __shfl_xor(pg, off, 64);
        }
        sarr[r] = pc * pc * fast_tanh(pg);
    }
#pragma unroll
    for (int j = 0; j < 4; ++j) {
        const float4* vpr = (const float4*)(Vph + (d0 + j) * 16);
        float a = 0.f;
#pragma unroll
        for (int rr = 0; rr < 4; ++rr) {
            float4 vv = vpr[rr];
            a += sarr[rr * 4] * vv.x + sarr[rr * 4 + 1] * vv.y + sarr[rr * 4 + 2] * vv.z + sarr[rr * 4 + 3] * vv.w;
        }
        kv[j] = -a + Fv[j] - gam[j] * vq[j];
    }
}

__global__ __launch_bounds__(256) void heun_kernel(
    const bf16* __restrict__ xnv, const bf16* __restrict__ gammab,
    const float* __restrict__ dtv, const float* __restrict__ F,
    const float* __restrict__ U, const float* __restrict__ Wx, const float* __restrict__ Vp,
    bf16* __restrict__ xcat, bf16* __restrict__ vcat) {
    const int t = blockIdx.x, tid = threadIdx.x;
    const int w = tid >> 6, lane = tid & 63, d0 = lane * 4;
    const size_t basep = (size_t)t * 2048 + w * 256 + d0;
    bf16x4 xh4 = *(const bf16x4*)(xnv + basep);
    bf16x4 vh4 = *(const bf16x4*)(xnv + basep + 1024);
    float4 Ff = *(const float4*)(F + (size_t)t * 1024 + w * 256 + d0);
    bf16x4 g4 = *(const bf16x4*)(gammab + (size_t)t * 1024 + w * 256 + d0);
    float xh[4], vh[4], gam[4], Fv[4] = {Ff.x, Ff.y, Ff.z, Ff.w};
#pragma unroll
    for (int j = 0; j < 4; ++j) {
        xh[j] = (float)xh4[j];
        vh[j] = (float)vh4[j];
        gam[j] = (float)g4[j];
    }
    const float dt = dtv[(size_t)t * 4 + w];
    const float* Uh = U + w * 4096;
    const float* Wxh = Wx + w * 4096;
    const float* Vph = Vp + w * 4096;
    float k1v[4], k2v[4], xe[4], ve[4];
    acc_eval(xh, vh, Uh, Wxh, Vph, d0, Fv, gam, k1v);
#pragma unroll
    for (int j = 0; j < 4; ++j) {
        xe[j] = xh[j] + dt * vh[j];
        ve[j] = vh[j] + dt * k1v[j];
    }
    acc_eval(xe, ve, Uh, Wxh, Vph, d0, Fv, gam, k2v);
    bf16x4 xo, vo;
#pragma unroll
    for (int j = 0; j < 4; ++j) {
        xo[j] = (bf16)(xh[j] + 0.5f * dt * (vh[j] + ve[j]));   // k1x=vh, k2x=ve
        vo[j] = (bf16)(vh[j] + 0.5f * dt * (k1v[j] + k2v[j]));
    }
    *(bf16x4*)(xcat + (size_t)t * 1024 + w * 256 + d0) = xo;
    *(bf16x4*)(vcat + (size_t)t * 1024 + w * 256 + d0) = vo;
}

// ---------------- K4: out = res + DEPTH_SCALE * (cat @ Wo), bf16 MFMA GEMM ----------------
// M=16384, N=1024, K=1024. grid (128, 8, 2); z picks x vs v stream.
__global__ __launch_bounds__(256) void out_gemm_kernel(
    const bf16* __restrict__ xcat, const bf16* __restrict__ vcat,
    const bf16* __restrict__ WoTx, const bf16* __restrict__ WoTv,
    const float* __restrict__ xres, const float* __restrict__ vres,
    float* __restrict__ outx, float* __restrict__ outv) {
    __shared__ bf16 sA[128 * 64];
    __shared__ bf16 sB[128 * 64];
    const int zsel = blockIdx.z;
    const bf16* A = zsel ? vcat : xcat;
    const bf16* Bt = zsel ? WoTv : WoTx;
    const float* res = zsel ? vres : xres;
    float* out = zsel ? outv : outx;
    const int tid = threadIdx.x, w = tid >> 6, lane = tid & 63;
    const int wm = w >> 1, wn = w & 1;
    const int m0 = blockIdx.x * 128, n0 = blockIdx.y * 128;
    const int lrow = lane >> 3, lcol = (lane & 7) * 8;
    const int nl = lane & 15, quad = lane >> 4;
    floatx4_t acc[4][4];
    const floatx4_t z4 = {0.f, 0.f, 0.f, 0.f};
#pragma unroll
    for (int mi = 0; mi < 4; ++mi)
#pragma unroll
        for (int ni = 0; ni < 4; ++ni) acc[mi][ni] = z4;
    for (int kt = 0; kt < 16; ++kt) {
        const int k0 = kt * 64;
#pragma unroll
        for (int i = 0; i < 4; ++i) {
            const int c = i * 4 + w;
            ld16(A + (size_t)(m0 + c * 8 + lrow) * 1024 + k0 + lcol, sA + c * 512);
            ld16(Bt + (size_t)(n0 + c * 8 + lrow) * 1024 + k0 + lcol, sB + c * 512);
        }
        __syncthreads();
#pragma unroll
        for (int kk = 0; kk < 2; ++kk) {
            bf16x8 af[4], bfr[4];
#pragma unroll
            for (int mi = 0; mi < 4; ++mi)
                af[mi] = *(const bf16x8*)(sA + (wm * 64 + mi * 16 + nl) * 64 + kk * 32 + quad * 8);
#pragma unroll
            for (int ni = 0; ni < 4; ++ni)
                bfr[ni] = *(const bf16x8*)(sB + (wn * 64 + ni * 16 + nl) * 64 + kk * 32 + quad * 8);
#pragma unroll
            for (int mi = 0; mi < 4; ++mi)
#pragma unroll
                for (int ni = 0; ni < 4; ++ni)
                    acc[mi][ni] = __builtin_amdgcn_mfma_f32_16x16x32_bf16(af[mi], bfr[ni], acc[mi][ni], 0, 0, 0);
        }
        __syncthreads();
    }
#pragma unroll
    for (int mi = 0; mi < 4; ++mi)
#pragma unroll
        for (int ni = 0; ni < 4; ++ni) {
            const int n = n0 + wn * 64 + ni * 16 + nl;
#pragma unroll
            for (int r = 0; r < 4; ++r) {
                const int m = m0 + wm * 64 + mi * 16 + quad * 4 + r;
                out[(size_t)m * 1024 + n] = res[(size_t)m * 1024 + n] + DEPTH_SCALE * acc[mi][ni][r];
            }
        }
}

extern "C" void kernel_launch(void* const* d_in, const int* in_sizes, int n_in,
                              void* d_out, int out_size, void* d_ws, size_t ws_size,
                              hipStream_t stream) {
    const float* x = (const float*)d_in[0];
    const float* v = (const float*)d_in[1];
    const float* F = (const float*)d_in[2];
    const float* lxg = (const float*)d_in[3];
    const float* lxb = (const float*)d_in[4];
    const float* lvg = (const float*)d_in[5];
    const float* lvb = (const float*)d_in[6];
    const float* U = (const float*)d_in[7];
    const float* Wx = (const float*)d_in[8];
    const float* Vp = (const float*)d_in[9];
    const float* gate_w = (const float*)d_in[10];
    const float* gate_b = (const float*)d_in[11];
    const float* fric_w = (const float*)d_in[12];
    const float* fric_b = (const float*)d_in[13];
    const float* dtp = (const float*)d_in[14];
    const float* Wox = (const float*)d_in[15];
    const float* Wov = (const float*)d_in[16];
    float* outx = (float*)d_out;
    float* outv = outx + (size_t)16384 * 1024;

    char* ws = (char*)d_ws;
    bf16* xnv = (bf16*)(ws);                       // [16384][2048] bf16 : xn | vn  (64 MB)
    bf16* gammab = (bf16*)(ws + 67108864);         // [16384][1024] bf16           (32 MB)
    bf16* xcat = (bf16*)(ws + 100663296);          // [16384][1024] bf16           (32 MB)
    bf16* vcat = (bf16*)(ws + 134217728);          // [16384][1024] bf16           (32 MB)
    bf16* WoTx = (bf16*)(ws + 167772160);          // [1024][1024] bf16 (B^T)      (2 MB)
    bf16* WoTv = (bf16*)(ws + 169869312);          // [1024][1024] bf16 (B^T)      (2 MB)
    bf16* fwt = (bf16*)(ws + 171966464);           // [4][256][512] bf16 (B^T)     (1 MB)
    float* dtv = (float*)(ws + 173015040);         // [16384][4] f32               (256 KB)

    dim3 tb(32, 8, 1);
    transpose_cast<<<dim3(32, 32, 1), tb, 0, stream>>>(Wox, WoTx, 1024, 1024);
    transpose_cast<<<dim3(32, 32, 1), tb, 0, stream>>>(Wov, WoTv, 1024, 1024);
    transpose_cast<<<dim3(8, 16, 4), tb, 0, stream>>>(fric_w, fwt, 512, 256);
    ln_gate_kernel<<<16384, 256, 0, stream>>>(x, v, lxg, lxb, lvg, lvb, gate_w, gate_b, dtp, xnv, dtv);
    gamma_gemm_kernel<<<dim3(128, 2, 4), 256, 0, stream>>>(xnv, fwt, fric_b, gammab);
    heun_kernel<<<16384, 256, 0, stream>>>(xnv, gammab, dtv, F, U, Wx, Vp, xcat, vcat);
    out_gemm_kernel<<<dim3(128, 8, 2), 256, 0, stream>>>(xcat, vcat, WoTx, WoTv, x, v, outx, outv);
}

// Round 2
// 572.017 us; speedup vs baseline: 1.3745x; 1.3745x over previous
//
#include <hip/hip_runtime.h>

typedef __bf16 bf16;
typedef __bf16 bf16x4 __attribute__((ext_vector_type(4)));
typedef __bf16 bf16x8 __attribute__((ext_vector_type(8)));
typedef float floatx4_t __attribute__((ext_vector_type(4)));
typedef unsigned int uint32x4 __attribute__((ext_vector_type(4)));

#define DEPTH_SCALE 0.4082482904638631f

__device__ __forceinline__ float fast_rcp(float x) { return __builtin_amdgcn_rcpf(x); }
__device__ __forceinline__ float fast_sigmoid(float x) { return fast_rcp(1.f + __expf(-x)); }
__device__ __forceinline__ float fast_tanh(float x) {
    float e = __expf(2.f * x);
    return 1.f - 2.f * fast_rcp(e + 1.f);
}
__device__ __forceinline__ float bf2f_lo(unsigned u) {
    union { unsigned u; float f; } c; c.u = u << 16; return c.f;
}
__device__ __forceinline__ float bf2f_hi(unsigned u) {
    union { unsigned u; float f; } c; c.u = u & 0xffff0000u; return c.f;
}

__device__ __forceinline__ void ld16(const void* g, void* l) {
    __builtin_amdgcn_global_load_lds((__attribute__((address_space(1))) void*)g,
                                     (__attribute__((address_space(3))) void*)l,
                                     16, 0, 0);
}

__device__ __forceinline__ float wave_reduce_add(float v) {
#pragma unroll
    for (int off = 1; off < 64; off <<= 1) v += __shfl_xor(v, off, 64);
    return v;
}

// s[16] dot 16 bf16 weights (2x bf16x8)
__device__ __forceinline__ float contract16(const bf16x8* vq, const float* s) {
    float g = 0.f;
#pragma unroll
    for (int hf = 0; hf < 2; ++hf) {
        uint32x4 u = __builtin_bit_cast(uint32x4, vq[hf]);
#pragma unroll
        for (int q = 0; q < 4; ++q) {
            g += s[hf * 8 + q * 2] * bf2f_lo(u[q]);
            g += s[hf * 8 + q * 2 + 1] * bf2f_hi(u[q]);
        }
    }
    return g;
}

// ---------------- K0: transpose + cast f32 -> bf16 (for Wo) ----------------
__global__ __launch_bounds__(256) void transpose_cast(const float* __restrict__ src,
                                                      bf16* __restrict__ dst,
                                                      int R, int C) {
    __shared__ float tile[32][33];
    const int b = blockIdx.z;
    src += (size_t)b * R * C;
    dst += (size_t)b * R * C;
    const int tx = threadIdx.x, ty = threadIdx.y;
    const int c0 = blockIdx.x * 32, r0 = blockIdx.y * 32;
#pragma unroll
    for (int i = 0; i < 4; ++i) {
        int r = r0 + ty + i * 8;
        tile[ty + i * 8][tx] = src[(size_t)r * C + c0 + tx];
    }
    __syncthreads();
#pragma unroll
    for (int i = 0; i < 4; ++i) {
        int c = c0 + ty + i * 8;
        dst[(size_t)c * R + r0 + tx] = (bf16)tile[tx][ty + i * 8];
    }
}

// ---------------- K0b: build extended B^T for gamma GEMM ----------------
// fwt2[h][n][k], n in [0,384), k in [0,512):
//   n<256         : fric_w[h][k][n]
//   256<=n<272    : r=n-256, k>=256 ? U[h][r][k-256] : 0      (c1 = vn.U^T)
//   272<=n<288    : r=n-272, k<256  ? Wx[h][r][k]    : 0      (g1 = xn.Wx^T)
//   288<=n<304    : r=n-288, k>=256 ? Wx[h][r][k-256]: 0      (vwx = vn.Wx^T)
//   n>=304        : 0
__global__ __launch_bounds__(256) void build_fwt2(const float* __restrict__ fric_w,
                                                  const float* __restrict__ U,
                                                  const float* __restrict__ Wx,
                                                  bf16* __restrict__ fwt2) {
    const int flat = blockIdx.x * 256 + threadIdx.x;  // 4*384*512
    const int k = flat & 511;
    const int rest = flat >> 9;
    const int h = rest / 384;
    const int n = rest - h * 384;
    float val = 0.f;
    if (n < 256) val = fric_w[(size_t)h * 512 * 256 + (size_t)k * 256 + n];
    else if (n < 272) { if (k >= 256) val = U[(h * 16 + n - 256) * 256 + k - 256]; }
    else if (n < 288) { if (k < 256)  val = Wx[(h * 16 + n - 272) * 256 + k]; }
    else if (n < 304) { if (k >= 256) val = Wx[(h * 16 + n - 288) * 256 + k - 256]; }
    fwt2[flat] = (bf16)val;
}

__global__ __launch_bounds__(256) void cast_bf16_kernel(const float* __restrict__ src,
                                                        bf16* __restrict__ dst, int n) {
    int i = blockIdx.x * 256 + threadIdx.x;
    if (i < n) dst[i] = (bf16)src[i];
}

// ---------------- K1: LayerNorm(x), LayerNorm(v), gate -> dt ----------------
__global__ __launch_bounds__(256) void ln_gate_kernel(
    const float* __restrict__ x, const float* __restrict__ v,
    const float* __restrict__ lxg, const float* __restrict__ lxb,
    const float* __restrict__ lvg, const float* __restrict__ lvb,
    const float* __restrict__ gate_w, const float* __restrict__ gate_b,
    const float* __restrict__ dt_params,
    bf16* __restrict__ xnv, float* __restrict__ dtv) {
    const int t = blockIdx.x, tid = threadIdx.x;
    const int w = tid >> 6, lane = tid & 63;
    float4 xv = ((const float4*)(x + (size_t)t * 1024))[tid];
    float4 vv = ((const float4*)(v + (size_t)t * 1024))[tid];
    float sx = xv.x + xv.y + xv.z + xv.w;
    float qx = xv.x * xv.x + xv.y * xv.y + xv.z * xv.z + xv.w * xv.w;
    float sv = vv.x + vv.y + vv.z + vv.w;
    float qv = vv.x * vv.x + vv.y * vv.y + vv.z * vv.z + vv.w * vv.w;
    sx = wave_reduce_add(sx); qx = wave_reduce_add(qx);
    sv = wave_reduce_add(sv); qv = wave_reduce_add(qv);
    __shared__ float red[16];
    if (lane == 0) { red[w] = sx; red[4 + w] = qx; red[8 + w] = sv; red[12 + w] = qv; }
    __syncthreads();
    sx = red[0] + red[1] + red[2] + red[3];
    qx = red[4] + red[5] + red[6] + red[7];
    sv = red[8] + red[9] + red[10] + red[11];
    qv = red[12] + red[13] + red[14] + red[15];
    const float inv = 1.f / 1024.f;
    const float mx = sx * inv, varx = qx * inv - mx * mx;
    const float mv = sv * inv, varv = qv * inv - mv * mv;
    const float rx = rsqrtf(varx + 1e-5f), rv = rsqrtf(varv + 1e-5f);
    float4 gx4 = ((const float4*)lxg)[tid], bx4 = ((const float4*)lxb)[tid];
    float4 gv4 = ((const float4*)lvg)[tid], bv4 = ((const float4*)lvb)[tid];
    float xn[4] = { (xv.x - mx) * rx * gx4.x + bx4.x, (xv.y - mx) * rx * gx4.y + bx4.y,
                    (xv.z - mx) * rx * gx4.z + bx4.z, (xv.w - mx) * rx * gx4.w + bx4.w };
    float vn[4] = { (vv.x - mv) * rv * gv4.x + bv4.x, (vv.y - mv) * rv * gv4.y + bv4.y,
                    (vv.z - mv) * rv * gv4.z + bv4.z, (vv.w - mv) * rv * gv4.w + bv4.w };
    bf16x4 xs, vs;
#pragma unroll
    for (int j = 0; j < 4; ++j) { xs[j] = (bf16)xn[j]; vs[j] = (bf16)vn[j]; }
    *(bf16x4*)(xnv + (size_t)t * 2048 + tid * 4) = xs;
    *(bf16x4*)(xnv + (size_t)t * 2048 + 1024 + tid * 4) = vs;
    const int d0 = lane * 4;
    float4 gwx = *(const float4*)(gate_w + w * 512 + d0);
    float4 gwv = *(const float4*)(gate_w + w * 512 + 256 + d0);
    float p = xn[0] * gwx.x + xn[1] * gwx.y + xn[2] * gwx.z + xn[3] * gwx.w
            + vn[0] * gwv.x + vn[1] * gwv.y + vn[2] * gwv.z + vn[3] * gwv.w;
    p = wave_reduce_add(p);
    if (lane == 0) {
        float z = p + gate_b[w];
        float sp = log1pf(__expf(dt_params[w]));
        dtv[(size_t)t * 4 + w] = sp * 2.f * fast_sigmoid(z);
    }
}

// ---------------- K2: extended gamma GEMM ----------------
// per head: M=16384, N=384 (256 fric + 16 c1 + 16 g1 + 16 vwx + 80 pad), K=512.
// grid (128, 3, 4).
__global__ __launch_bounds__(256) void gamma_gemm_kernel(
    const bf16* __restrict__ xnv, const bf16* __restrict__ fwt2,
    const float* __restrict__ fric_b, bf16* __restrict__ gamx,
    bf16* __restrict__ aux) {
    __shared__ bf16 sA[128 * 64];
    __shared__ bf16 sB[128 * 64];
    const int tid = threadIdx.x, w = tid >> 6, lane = tid & 63;
    const int wm = w >> 1, wn = w & 1;
    const int m0 = blockIdx.x * 128, n0 = blockIdx.y * 128, h = blockIdx.z;
    const int lrow = lane >> 3, lcol = (lane & 7) * 8;
    const int nl = lane & 15, quad = lane >> 4;
    floatx4_t acc[4][4];
    const floatx4_t z4 = {0.f, 0.f, 0.f, 0.f};
#pragma unroll
    for (int mi = 0; mi < 4; ++mi)
#pragma unroll
        for (int ni = 0; ni < 4; ++ni) acc[mi][ni] = z4;
    const bf16* Bh = fwt2 + (size_t)h * 384 * 512;
    for (int kt = 0; kt < 8; ++kt) {
        const int kg = kt * 64;
        const int colbase = (kg < 256) ? (h * 256 + kg) : (1024 + h * 256 + kg - 256);
#pragma unroll
        for (int i = 0; i < 4; ++i) {
            const int c = i * 4 + w;
            ld16(xnv + (size_t)(m0 + c * 8 + lrow) * 2048 + colbase + lcol, sA + c * 512);
            ld16(Bh + (size_t)(n0 + c * 8 + lrow) * 512 + kg + lcol, sB + c * 512);
        }
        __syncthreads();
#pragma unroll
        for (int kk = 0; kk < 2; ++kk) {
            bf16x8 af[4], bfr[4];
#pragma unroll
            for (int mi = 0; mi < 4; ++mi)
                af[mi] = *(const bf16x8*)(sA + (wm * 64 + mi * 16 + nl) * 64 + kk * 32 + quad * 8);
#pragma unroll
            for (int ni = 0; ni < 4; ++ni)
                bfr[ni] = *(const bf16x8*)(sB + (wn * 64 + ni * 16 + nl) * 64 + kk * 32 + quad * 8);
#pragma unroll
            for (int mi = 0; mi < 4; ++mi)
#pragma unroll
                for (int ni = 0; ni < 4; ++ni)
                    acc[mi][ni] = __builtin_amdgcn_mfma_f32_16x16x32_bf16(af[mi], bfr[ni], acc[mi][ni], 0, 0, 0);
        }
        __syncthreads();
    }
#pragma unroll
    for (int mi = 0; mi < 4; ++mi)
#pragma unroll
        for (int ni = 0; ni < 4; ++ni) {
            const int n = n0 + wn * 64 + ni * 16 + nl;
            if (n < 256) {
                const float fb = fric_b[h * 256 + n];
#pragma unroll
                for (int r = 0; r < 4; ++r) {
                    const int m = m0 + wm * 64 + mi * 16 + quad * 4 + r;
                    gamx[(size_t)m * 1024 + h * 256 + n] = (bf16)fast_sigmoid(acc[mi][ni][r] + fb);
                }
            } else if (n < 304) {
#pragma unroll
                for (int r = 0; r < 4; ++r) {
                    const int m = m0 + wm * 64 + mi * 16 + quad * 4 + r;
                    aux[(size_t)m * 256 + h * 64 + (n - 256)] = (bf16)acc[mi][ni][r];
                }
            }
        }
}

// ---------------- K3: Heun RK2 ----------------
// grid 2048, block 256. Wave w = head w, 8 tokens per wave. No __syncthreads.
// Lane roles: phase-R (sub=lane>>4, r=lane&15) for the c2 dot; phase-D (d0=lane*4) elsewhere.
// gamx: gamma read, x_cat written in place (per-lane read-then-write, exact partition).
__global__ __launch_bounds__(256) void heun_kernel(
    const bf16* __restrict__ xnv, bf16* __restrict__ gamx,
    const bf16* __restrict__ aux, const float* __restrict__ dtv,
    const float* __restrict__ F, const bf16* __restrict__ fwt2,
    const bf16* __restrict__ Vpbf, bf16* __restrict__ vcat) {
    __shared__ float smem[4][304];  // per wave: [0..279] ve (stride-72/sub), [280..295] s-buf
    const int tid = threadIdx.x, h = tid >> 6, lane = tid & 63;
    const int sub = lane >> 4, r = lane & 15, d0 = lane * 4;
    float* vb = smem[h];
    const int waddr = d0 + sub * 8;
    // cached weights (bf16 in regs)
    bf16x8 Ub[8];
    const bf16* ubase = fwt2 + ((size_t)h * 384 + 256 + r) * 512 + 256 + sub * 64;
#pragma unroll
    for (int j = 0; j < 8; ++j) Ub[j] = *(const bf16x8*)(ubase + j * 8);
    bf16x8 Vq[4][2];
#pragma unroll
    for (int dd = 0; dd < 4; ++dd)
#pragma unroll
        for (int q = 0; q < 2; ++q)
            Vq[dd][q] = *(const bf16x8*)(Vpbf + ((h * 256 + d0 + dd) * 16) + q * 8);
    const int t0 = blockIdx.x * 8;
    for (int i = 0; i < 8; ++i) {
        const int t = t0 + i;
        const size_t tb2 = (size_t)t * 2048 + h * 256 + d0;
        const size_t tb1 = (size_t)t * 1024 + h * 256 + d0;
        bf16x4 xh4 = *(const bf16x4*)(xnv + tb2);
        bf16x4 vh4 = *(const bf16x4*)(xnv + tb2 + 1024);
        bf16x4 g4 = *(const bf16x4*)(gamx + tb1);
        float4 F4 = *(const float4*)(F + tb1);
        const float dt = dtv[t * 4 + h];
        const bf16* ax = aux + (size_t)t * 256 + h * 64;
        const float c1 = (float)ax[r];
        const float g1raw = (float)ax[16 + r];
        const float vwx = (float)ax[32 + r];
        float xhF[4], vhF[4], gamF[4];
#pragma unroll
        for (int dd = 0; dd < 4; ++dd) {
            xhF[dd] = (float)xh4[dd]; vhF[dd] = (float)vh4[dd]; gamF[dd] = (float)g4[dd];
        }
        // eval1: s1 from precomputed c1,g1 (phase-R), broadcast via LDS
        const float s1 = c1 * c1 * fast_tanh(g1raw);
        if (sub == 0) vb[280 + r] = s1;
        float sa[16];
        {
            const float4* sb4 = (const float4*)(vb + 280);
#pragma unroll
            for (int q = 0; q < 4; ++q) *(float4*)(sa + q * 4) = sb4[q];
        }
        float k1v[4], ve[4];
#pragma unroll
        for (int dd = 0; dd < 4; ++dd) {
            const float gv = contract16(Vq[dd], sa);
            k1v[dd] = F4[dd * 0 + dd] - gv - gamF[dd] * vhF[dd];
            ve[dd] = vhF[dd] + dt * k1v[dd];
        }
        // redistribute ve -> phase-R slices
        floatx4_t vef = {ve[0], ve[1], ve[2], ve[3]};
        *(floatx4_t*)(vb + waddr) = vef;
        // eval2 dot: c2 = sum_d ve[d] * U[r][d]
        float c2 = 0.f;
        const float* vsl = vb + sub * 72;
#pragma unroll
        for (int j = 0; j < 8; ++j) {
            float4 va = *(const float4*)(vsl + j * 8);
            float4 vbb = *(const float4*)(vsl + j * 8 + 4);
            uint32x4 u = __builtin_bit_cast(uint32x4, Ub[j]);
            c2 += va.x * bf2f_lo(u[0]) + va.y * bf2f_hi(u[0])
                + va.z * bf2f_lo(u[1]) + va.w * bf2f_hi(u[1])
                + vbb.x * bf2f_lo(u[2]) + vbb.y * bf2f_hi(u[2])
                + vbb.z * bf2f_lo(u[3]) + vbb.w * bf2f_hi(u[3]);
        }
        c2 += __shfl_xor(c2, 16, 64);
        c2 += __shfl_xor(c2, 32, 64);
        // g2 = tanh(g1raw + dt*vwx)  (linearity of xe.Wx)
        const float g2t = fast_tanh(g1raw + dt * vwx);
        const float s2 = c2 * c2 * g2t;
        if (sub == 0) vb[280 + r] = s2;
        {
            const float4* sb4 = (const float4*)(vb + 280);
#pragma unroll
            for (int q = 0; q < 4; ++q) *(float4*)(sa + q * 4) = sb4[q];
        }
        bf16x4 xo, vo;
#pragma unroll
        for (int dd = 0; dd < 4; ++dd) {
            const float gv2 = contract16(Vq[dd], sa);
            const float k2v = F4[dd] - gv2 - gamF[dd] * ve[dd];
            xo[dd] = (bf16)(xhF[dd] + 0.5f * dt * (vhF[dd] + ve[dd]));
            vo[dd] = (bf16)(vhF[dd] + 0.5f * dt * (k1v[dd] + k2v));
        }
        *(bf16x4*)(gamx + tb1) = xo;   // x_cat overwrites gamma slot
        *(bf16x4*)(vcat + tb1) = vo;
    }
}

// ---------------- K4: out = res + DEPTH_SCALE * (cat @ Wo) ----------------
__global__ __launch_bounds__(256) void out_gemm_kernel(
    const bf16* __restrict__ xcat, const bf16* __restrict__ vcat,
    const bf16* __restrict__ WoTx, const bf16* __restrict__ WoTv,
    const float* __restrict__ xres, const float* __restrict__ vres,
    float* __restrict__ outx, float* __restrict__ outv) {
    __shared__ bf16 sA[128 * 64];
    __shared__ bf16 sB[128 * 64];
    const int zsel = blockIdx.z;
    const bf16* A = zsel ? vcat : xcat;
    const bf16* Bt = zsel ? WoTv : WoTx;
    const float* res = zsel ? vres : xres;
    float* out = zsel ? outv : outx;
    const int tid = threadIdx.x, w = tid >> 6, lane = tid & 63;
    const int wm = w >> 1, wn = w & 1;
    const int m0 = blockIdx.x * 128, n0 = blockIdx.y * 128;
    const int lrow = lane >> 3, lcol = (lane & 7) * 8;
    const int nl = lane & 15, quad = lane >> 4;
    floatx4_t acc[4][4];
    const floatx4_t z4 = {0.f, 0.f, 0.f, 0.f};
#pragma unroll
    for (int mi = 0; mi < 4; ++mi)
#pragma unroll
        for (int ni = 0; ni < 4; ++ni) acc[mi][ni] = z4;
    for (int kt = 0; kt < 16; ++kt) {
        const int k0 = kt * 64;
#pragma unroll
        for (int i = 0; i < 4; ++i) {
            const int c = i * 4 + w;
            ld16(A + (size_t)(m0 + c * 8 + lrow) * 1024 + k0 + lcol, sA + c * 512);
            ld16(Bt + (size_t)(n0 + c * 8 + lrow) * 1024 + k0 + lcol, sB + c * 512);
        }
        __syncthreads();
#pragma unroll
        for (int kk = 0; kk < 2; ++kk) {
            bf16x8 af[4], bfr[4];
#pragma unroll
            for (int mi = 0; mi < 4; ++mi)
                af[mi] = *(const bf16x8*)(sA + (wm * 64 + mi * 16 + nl) * 64 + kk * 32 + quad * 8);
#pragma unroll
            for (int ni = 0; ni < 4; ++ni)
                bfr[ni] = *(const bf16x8*)(sB + (wn * 64 + ni * 16 + nl) * 64 + kk * 32 + quad * 8);
#pragma unroll
            for (int mi = 0; mi < 4; ++mi)
#pragma unroll
                for (int ni = 0; ni < 4; ++ni)
                    acc[mi][ni] = __builtin_amdgcn_mfma_f32_16x16x32_bf16(af[mi], bfr[ni], acc[mi][ni], 0, 0, 0);
        }
        __syncthreads();
    }
#pragma unroll
    for (int mi = 0; mi < 4; ++mi)
#pragma unroll
        for (int ni = 0; ni < 4; ++ni) {
            const int n = n0 + wn * 64 + ni * 16 + nl;
#pragma unroll
            for (int r = 0; r < 4; ++r) {
                const int m = m0 + wm * 64 + mi * 16 + quad * 4 + r;
                out[(size_t)m * 1024 + n] = res[(size_t)m * 1024 + n] + DEPTH_SCALE * acc[mi][ni][r];
            }
        }
}

extern "C" void kernel_launch(void* const* d_in, const int* in_sizes, int n_in,
                              void* d_out, int out_size, void* d_ws, size_t ws_size,
                              hipStream_t stream) {
    const float* x = (const float*)d_in[0];
    const float* v = (const float*)d_in[1];
    const float* F = (const float*)d_in[2];
    const float* lxg = (const float*)d_in[3];
    const float* lxb = (const float*)d_in[4];
    const float* lvg = (const float*)d_in[5];
    const float* lvb = (const float*)d_in[6];
    const float* U = (const float*)d_in[7];
    const float* Wx = (const float*)d_in[8];
    const float* Vp = (const float*)d_in[9];
    const float* gate_w = (const float*)d_in[10];
    const float* gate_b = (const float*)d_in[11];
    const float* fric_w = (const float*)d_in[12];
    const float* fric_b = (const float*)d_in[13];
    const float* dtp = (const float*)d_in[14];
    const float* Wox = (const float*)d_in[15];
    const float* Wov = (const float*)d_in[16];
    float* outx = (float*)d_out;
    float* outv = outx + (size_t)16384 * 1024;

    char* ws = (char*)d_ws;
    bf16* xnv  = (bf16*)(ws);                        // [16384][2048] bf16 (64 MB)
    bf16* gamx = (bf16*)(ws + 67108864);             // [16384][1024] bf16: gamma then x_cat (32 MB)
    bf16* vcat = (bf16*)(ws + 100663296);            // [16384][1024] bf16 (32 MB)
    bf16* WoTx = (bf16*)(ws + 134217728);            // [1024][1024] bf16 (2 MB)
    bf16* WoTv = (bf16*)(ws + 136314880);            // [1024][1024] bf16 (2 MB)
    bf16* fwt2 = (bf16*)(ws + 138412032);            // [4][384][512] bf16 (1.5 MB)
    bf16* Vpbf = (bf16*)(ws + 139984896);            // [4][256][16] bf16 (32 KB)
    bf16* aux  = (bf16*)(ws + 140017664);            // [16384][256] bf16: c1|g1|vwx per head (8 MB)
    float* dtv = (float*)(ws + 148406272);           // [16384][4] f32 (256 KB)

    dim3 tb(32, 8, 1);
    transpose_cast<<<dim3(32, 32, 1), tb, 0, stream>>>(Wox, WoTx, 1024, 1024);
    transpose_cast<<<dim3(32, 32, 1), tb, 0, stream>>>(Wov, WoTv, 1024, 1024);
    build_fwt2<<<3072, 256, 0, stream>>>(fric_w, U, Wx, fwt2);
    cast_bf16_kernel<<<64, 256, 0, stream>>>(Vp, Vpbf, 16384);
    ln_gate_kernel<<<16384, 256, 0, stream>>>(x, v, lxg, lxb, lvg, lvb, gate_w, gate_b, dtp, xnv, dtv);
    gamma_gemm_kernel<<<dim3(128, 3, 4), 256, 0, stream>>>(xnv, fwt2, fric_b, gamx, aux);
    heun_kernel<<<2048, 256, 0, stream>>>(xnv, gamx, aux, dtv, F, fwt2, Vpbf, vcat);
    out_gemm_kernel<<<dim3(128, 8, 2), 256, 0, stream>>>(gamx, vcat, WoTx, WoTv, x, v, outx, outv);
}